// Round 6
// baseline (353.169 us; speedup 1.0000x reference)
//
#include <hip/hip_runtime.h>
#include <hip/hip_fp16.h>

// NeuronToSpatialGrid R8: K=128 rounds (32 total) — 8 MFMA/wave/round to amortize
// the measured ~1400 cyc/round fixed overhead (R7 postmortem: not LDS-BW-bound).
// Row-sum removed from GEMM loop: denominator precomputed in prep (f16-product
// rounding replicated). Triple-buffered 16KB stages, counted vmcnt(4)/round.

typedef __attribute__((ext_vector_type(8))) _Float16 half8;
typedef __attribute__((ext_vector_type(4))) float floatx4;
typedef __attribute__((ext_vector_type(16))) float floatx16;

#define NB 4
#define NN 4096
#define NE 256
#define NP 4096

#define MFMA32(a, bb, c) __builtin_amdgcn_mfma_f32_32x32x16_f16(a, bb, c, 0, 0, 0)

__device__ __forceinline__ void gload_lds16(const void* g, void* l) {
    __builtin_amdgcn_global_load_lds((const __attribute__((address_space(1))) void*)g,
                                     (__attribute__((address_space(3))) void*)l, 16, 0, 0);
}

// ---------- prep:
// region [0,1024):    F [B][N][E] f32 -> FT frag order
//   idx = (((b*256+kb)*8+eb)*64+l)*8+j = F[b][kb*16+(l>>5)*8+j][eb*32+(l&31)]
// region [1024,2048): EY frag order
//   idx = (((b*256+kb)*2+rt)*64+l)*8+j = exp(-50*(r/63-y_k)^2), r=rt*32+(l&31), k=kb*16+(l>>5)*8+j
// region [2048,3072): S[b][gx*64+gy] partial sums (atomicAdd), f16-product rounding
__global__ __launch_bounds__(256) void prep(const float* __restrict__ in,
                                            const float* __restrict__ pos,
                                            __half* __restrict__ ft,
                                            __half* __restrict__ EYf,
                                            float* __restrict__ SG) {
    __shared__ float tile[128][33];
    __shared__ float red[4][64];
    const int bb  = blockIdx.x;
    const int tid = threadIdx.x;
    if (bb < 1024) {
        const int bx = bb & 31, eb2 = (bb >> 5) & 7, b = bb >> 8;
        const int n0 = bx * 128;
        const int rn = tid >> 3, re = (tid & 7) * 4;
#pragma unroll
        for (int p = 0; p < 4; p++) {
            const int n = p * 32 + rn;
            float4 v = *(const float4*)&in[(size_t)(b * NN + n0 + n) * NE + eb2 * 32 + re];
            tile[n][re] = v.x; tile[n][re + 1] = v.y; tile[n][re + 2] = v.z; tile[n][re + 3] = v.w;
        }
        __syncthreads();
#pragma unroll
        for (int i = 0; i < 2; i++) {
            const int c = i * 256 + tid;
            const int l = c & 63, kb_l = c >> 6;
            const int nbase = kb_l * 16 + ((l >> 5) << 3);
            const int col = l & 31;
            __half hh[8];
#pragma unroll
            for (int j = 0; j < 8; j++) hh[j] = __float2half_rn(tile[nbase + j][col]);
            const size_t idx = ((((size_t)b * 256 + (size_t)bx * 8 + kb_l) * 8 + eb2) * 64 + l) * 8;
            *(uint4*)&ft[idx] = *(const uint4*)hh;
        }
    } else if (bb < 2048) {
        const int base = (bb - 1024) * 1024 + tid * 4;
        const int j0 = base & 7;
        const int l  = (base >> 3) & 63;
        const int rt = (base >> 9) & 1;
        const int kb = (base >> 10) & 255;
        const int b  = base >> 18;
        const int r  = rt * 32 + (l & 31);
        const int k0 = kb * 16 + ((l >> 5) << 3) + j0;
        const float ry = (float)r * (1.0f / 63.0f);
        __half hh[4];
#pragma unroll
        for (int jj = 0; jj < 4; jj++) {
            const float y = pos[((size_t)b * NN + k0 + jj) * 2 + 1];
            const float d = ry - y;
            hh[jj] = __float2half_rn(__expf(d * d * -50.0f));
        }
        *(uint2*)&EYf[base] = *(const uint2*)hh;
    } else {
        const int idx = bb - 2048;           // 0..1023
        const int b   = idx >> 8;
        const int gx  = (idx >> 2) & 63;
        const int kh  = idx & 3;             // k-quarter of 1024
        const int gy  = tid & 63, kq = tid >> 6;
        const float gxv = (float)gx * (1.0f / 63.0f);
        const float gyv = (float)gy * (1.0f / 63.0f);
        const float2* pb = (const float2*)(pos + (size_t)b * NN * 2);
        float s = 0.f;
        const int kbase = kh * 1024 + kq * 256;
#pragma unroll 4
        for (int i = 0; i < 256; ++i) {
            const float2 p2 = pb[kbase + i];
            const float dx = gxv - p2.x, dy = gyv - p2.y;
            const _Float16 exh = (_Float16)__expf(dx * dx * -50.0f);
            const _Float16 eyh = (_Float16)__expf(dy * dy * -50.0f);
            s += (float)(_Float16)(exh * eyh);   // replicate GEMM's f16 product rounding
        }
        red[kq][gy] = s;
        __syncthreads();
        if (tid < 64) {
            const float tot = red[0][tid] + red[1][tid] + red[2][tid] + red[3][tid];
            atomicAdd(&SG[(size_t)b * 4096 + gx * 64 + tid], tot);
        }
    }
}

// ---------- fused GEMM. 512 blocks x 512 thr (2 blocks/CU), 32 rounds of K=128.
// Wave (g = m-half, kw = k-quarter): 8 MFMAs/round on 64m x 64e tile.
// vmcnt ledger/round: top: [ey(r+1) x4 outstanding]; issue stage(r+2) x2;
//   a-compute consumes ey(r+1) (compiler vmcnt(2), stage stays in flight);
//   issue ey(r+2) x4; end: vmcnt(4) forces stage(r+2), leaves ey(r+2). 1 barrier.
__global__ __launch_bounds__(512, 4) void nw_gemm(const __half* __restrict__ FT,
                                                  const __half* __restrict__ EYf,
                                                  const float* __restrict__ pos,
                                                  const float* __restrict__ SG,
                                                  float* __restrict__ out) {
    __shared__ __half Bs[3][8192];       // 48 KB triple-buffered B tiles (16 KB each)
    __shared__ __half exb[2][4096];      // 16 KB ex rows (gx = 2mblk+g)
    __shared__ float Sinv_s[128];

    const int bid  = blockIdx.x;
    const int xcd  = bid & 7;            // pin (b, e-half) per XCD
    const int b    = xcd >> 1;
    const int etp  = xcd & 1;
    const int rest = bid >> 3;
    const int et   = etp * 2 + (rest & 1);   // e-quarter (64 e)
    const int mblk = rest >> 1;              // 0..31
    const int tid  = threadIdx.x;
    const int wave = tid >> 6, lane = tid & 63;
    const int g   = wave & 1;                // m-half
    const int kw  = wave >> 1;               // k-quarter of 128
    const int hi8 = (lane >> 5) << 3;

    // staging: thread t stages chunks c0s and c0s+4 (kb-rel within round tile)
    const int c0s  = tid >> 7;               // 0..3
    const int o128 = (tid & 127) * 8;
    const __half* ftb = FT + ((size_t)b * 1048576) + (size_t)c0s * 4096 + et * 1024 + o128;
    __half* const bd  = &Bs[0][0];           // buffer base; chunk dst = buf + c0s*1024 (+4096)

    const __half* eyW = EYf + ((size_t)b << 18) + (size_t)lane * 8;
    const int rdO = kw * 2048 + lane * 8;
    const __half* exg = exb[g];

#define STAGE(rr, BUF_) do {                                                        \
        gload_lds16(ftb + (size_t)(rr) * 32768,         (BUF_) + c0s * 1024 + o128); \
        gload_lds16(ftb + (size_t)(rr) * 32768 + 16384, (BUF_) + c0s * 1024 + 4096 + o128); \
    } while (0)

    // ---- prologue
    STAGE(0, &Bs[0][0]);
    STAGE(1, &Bs[1][0]);
    half8 eyN0 = *(const half8*)(eyW + (size_t)(2 * kw) * 1024);
    half8 eyN1 = *(const half8*)(eyW + (size_t)(2 * kw) * 1024 + 512);
    half8 eyN2 = *(const half8*)(eyW + (size_t)(2 * kw) * 1024 + 1024);
    half8 eyN3 = *(const half8*)(eyW + (size_t)(2 * kw) * 1024 + 1536);
    if (tid < 128) {
        const float sg = SG[(size_t)b * 4096 + mblk * 128 + tid];
        Sinv_s[tid] = 1.0f / (sg + 1e-8f);
    }
    {   // ex rows: gx = 2mblk, 2mblk+1
        const float* pb = pos + (size_t)b * NN * 2;
        const float gx0 = (float)(mblk * 2)     * (1.0f / 63.0f);
        const float gx1 = (float)(mblk * 2 + 1) * (1.0f / 63.0f);
        for (int k = tid; k < NN; k += 512) {
            const float x = pb[2 * k];
            const float d0 = gx0 - x, d1 = gx1 - x;
            exb[0][k] = __float2half_rn(__expf(d0 * d0 * -50.0f));
            exb[1][k] = __float2half_rn(__expf(d1 * d1 * -50.0f));
        }
    }
    __syncthreads();   // stage(0),(1), ey(0), Sinv landed; ex ready

    floatx16 acc00 = {}, acc01 = {}, acc10 = {}, acc11 = {};

    half8 bfA0, bfA1, bfA2, bfA3, bfB0, bfB1, bfB2, bfB3;
    half8 aA0, aA1, aA2, aA3, aB0, aB1, aB2, aB3;
    half8 exN0, exN1;

    // frags(0) from Bs0 + a(0) = ex(0)*ey(0)
    bfA0 = *(const half8*)(&Bs[0][0] + rdO);
    bfA1 = *(const half8*)(&Bs[0][0] + rdO + 512);
    bfA2 = *(const half8*)(&Bs[0][0] + rdO + 1024);
    bfA3 = *(const half8*)(&Bs[0][0] + rdO + 1536);
    {
        half8 e0 = *(const half8*)(exg + kw * 32 + hi8);
        half8 e1 = *(const half8*)(exg + kw * 32 + 16 + hi8);
        aA0 = e0 * eyN0; aA1 = e0 * eyN1;
        aA2 = e1 * eyN2; aA3 = e1 * eyN3;
    }
    // ey(1) prefetch
    {
        const __half* eyR = eyW + (size_t)(8 + 2 * kw) * 1024;
        eyN0 = *(const half8*)(eyR);
        eyN1 = *(const half8*)(eyR + 512);
        eyN2 = *(const half8*)(eyR + 1024);
        eyN3 = *(const half8*)(eyR + 1536);
    }

#define ROUND(r_, RB_, SB_, A0,A1,A2,A3, B0,B1,B2,B3, NA0,NA1,NA2,NA3, NB0,NB1,NB2,NB3) do { \
    if ((r_) < 30) STAGE((r_) + 2, SB_);                                       \
    __builtin_amdgcn_sched_barrier(0);                                         \
    if ((r_) < 31) {                                                           \
        NB0 = *(const half8*)((RB_) + rdO);                                    \
        NB1 = *(const half8*)((RB_) + rdO + 512);                              \
        NB2 = *(const half8*)((RB_) + rdO + 1024);                             \
        NB3 = *(const half8*)((RB_) + rdO + 1536);                             \
        exN0 = *(const half8*)(exg + ((r_) + 1) * 128 + kw * 32 + hi8);        \
        exN1 = *(const half8*)(exg + ((r_) + 1) * 128 + kw * 32 + 16 + hi8);   \
    }                                                                          \
    __builtin_amdgcn_s_setprio(1);                                             \
    acc00 = MFMA32(A0, B0, acc00);                                             \
    acc01 = MFMA32(A0, B1, acc01);                                             \
    acc10 = MFMA32(A1, B0, acc10);                                             \
    acc11 = MFMA32(A1, B1, acc11);                                             \
    acc00 = MFMA32(A2, B2, acc00);                                             \
    acc01 = MFMA32(A2, B3, acc01);                                             \
    acc10 = MFMA32(A3, B2, acc10);                                             \
    acc11 = MFMA32(A3, B3, acc11);                                             \
    __builtin_amdgcn_s_setprio(0);                                             \
    if ((r_) < 31) {                                                           \
        NA0 = exN0 * eyN0; NA1 = exN0 * eyN1;                                  \
        NA2 = exN1 * eyN2; NA3 = exN1 * eyN3;                                  \
    }                                                                          \
    __builtin_amdgcn_sched_barrier(0);                                         \
    if ((r_) < 30) {                                                           \
        const __half* eyR_ = eyW + (size_t)(8 * ((r_) + 2) + 2 * kw) * 1024;   \
        eyN0 = *(const half8*)(eyR_);                                          \
        eyN1 = *(const half8*)(eyR_ + 512);                                    \
        eyN2 = *(const half8*)(eyR_ + 1024);                                   \
        eyN3 = *(const half8*)(eyR_ + 1536);                                   \
    }                                                                          \
    __builtin_amdgcn_sched_barrier(0);                                         \
    if ((r_) < 31) { asm volatile("s_waitcnt vmcnt(4)" ::: "memory"); }        \
    else           { asm volatile("s_waitcnt vmcnt(0)" ::: "memory"); }        \
    __builtin_amdgcn_s_barrier();                                              \
} while (0)

    __half *px = &Bs[0][0], *py = &Bs[1][0], *pz = &Bs[2][0];
    for (int t = 0; t < 16; ++t) {
        const int r0 = 2 * t;
        ROUND(r0,     py, pz, aA0,aA1,aA2,aA3, bfA0,bfA1,bfA2,bfA3,
                              aB0,aB1,aB2,aB3, bfB0,bfB1,bfB2,bfB3);
        ROUND(r0 + 1, pz, px, aB0,aB1,aB2,aB3, bfB0,bfB1,bfB2,bfB3,
                              aA0,aA1,aA2,aA3, bfA0,bfA1,bfA2,bfA3);
        __half* tmp = pz; pz = py; py = px; px = tmp;   // (x,y,z) <- (z,x,y)
    }
#undef ROUND
#undef STAGE

    __syncthreads();

    // ---- k-split reduce through freed Bs pool (48 KB) + normalize + store.
    // D layout: col(e)=lane&31, row = (reg&3) + 8*(reg>>2) + 4*(lane>>5)
    float* RS = (float*)&Bs[0][0];   // 12288 floats

#define RSWRITE(A0_, A1_) do {                                                    \
        if (kw > 0) {                                                             \
            *(floatx16*)&RS[((0 * 2 + g) * 3 + (kw - 1)) * 1024 + lane * 16] = A0_; \
            *(floatx16*)&RS[((1 * 2 + g) * 3 + (kw - 1)) * 1024 + lane * 16] = A1_; \
        }                                                                         \
    } while (0)

#define RSREDUCE(A0_, A1_, RT_) do {                                              \
        if (kw == 0) {                                                            \
            _Pragma("unroll")                                                     \
            for (int qq = 0; qq < 2; qq++) {                                      \
                floatx16 a = qq ? A1_ : A0_;                                      \
                const int rb = ((qq * 2 + g) * 3) * 1024 + lane * 16;             \
                a += *(const floatx16*)&RS[rb];                                   \
                a += *(const floatx16*)&RS[rb + 1024];                            \
                a += *(const floatx16*)&RS[rb + 2048];                            \
                const int e = et * 64 + qq * 32 + (lane & 31);                    \
                float* orow = out + ((size_t)b * NE + e) * NP                     \
                                  + mblk * 128 + g * 64 + (RT_) * 32;             \
                _Pragma("unroll")                                                 \
                for (int q = 0; q < 4; ++q) {                                     \
                    const int pr = q * 8 + ((lane >> 5) << 2);                    \
                    const floatx4 sv = *(const floatx4*)&Sinv_s[g * 64 + (RT_) * 32 + pr]; \
                    floatx4 o;                                                    \
                    o.x = a[q * 4 + 0] * sv.x; o.y = a[q * 4 + 1] * sv.y;         \
                    o.z = a[q * 4 + 2] * sv.z; o.w = a[q * 4 + 3] * sv.w;         \
                    *(floatx4*)&orow[pr] = o;                                     \
                }                                                                 \
            }                                                                     \
        }                                                                         \
    } while (0)

    RSWRITE(acc00, acc01);
    __syncthreads();
    RSREDUCE(acc00, acc01, 0);
    __syncthreads();
    RSWRITE(acc10, acc11);
    __syncthreads();
    RSREDUCE(acc10, acc11, 1);

#undef RSWRITE
#undef RSREDUCE
}

extern "C" void kernel_launch(void* const* d_in, const int* in_sizes, int n_in,
                              void* d_out, int out_size, void* d_ws, size_t ws_size,
                              hipStream_t stream) {
    const float* feat = (const float*)d_in[0];   // [4][4096][256] f32
    const float* pos  = (const float*)d_in[1];   // [4][4096][2]  f32
    float* out = (float*)d_out;                  // [4][256][4096] f32
    __half* FT  = (__half*)d_ws;                                       // 8.39 MB
    __half* EYf = (__half*)((char*)d_ws + 8388608);                    // +2.10 MB
    float*  SG  = (float*)((char*)d_ws + 8388608 + 2097152);           // +64 KB

    hipMemsetAsync(SG, 0, (size_t)NB * 4096 * sizeof(float), stream);
    hipLaunchKernelGGL(prep, dim3(3072), dim3(256), 0, stream, feat, pos, FT, EYf, SG);
    hipLaunchKernelGGL(nw_gemm, dim3(512), dim3(512), 0, stream, FT, EYf, pos, SG, out);
}

// Round 7
// 159.757 us; speedup vs baseline: 2.2107x; 2.2107x over previous
//
#include <hip/hip_runtime.h>
#include <hip/hip_fp16.h>

// NeuronToSpatialGrid R9: R7's proven register set (124 regs, no spill) + barrier
// every 2nd K-64 sub-round (32 spans). 6-buffer LDS rotation (shift 2/span),
// glds lookahead +4, prologue stages 4 tiles. Denominator via SG precompute in
// prep (R8, verified) — no sum8 in the GEMM loop.

typedef __attribute__((ext_vector_type(8))) _Float16 half8;
typedef __attribute__((ext_vector_type(4))) float floatx4;
typedef __attribute__((ext_vector_type(16))) float floatx16;

#define NB 4
#define NN 4096
#define NE 256
#define NP 4096

#define MFMA32(a, bb, c) __builtin_amdgcn_mfma_f32_32x32x16_f16(a, bb, c, 0, 0, 0)

__device__ __forceinline__ void gload_lds16(const void* g, void* l) {
    __builtin_amdgcn_global_load_lds((const __attribute__((address_space(1))) void*)g,
                                     (__attribute__((address_space(3))) void*)l, 16, 0, 0);
}

// ---------- prep (identical to R8, verified):
// [0,1024):    F [B][N][E] f32 -> FT frag order
// [1024,2048): EY frag order
// [2048,3072): SG[b][gx*64+gy] row-sum partials (atomicAdd), f16-product rounding
__global__ __launch_bounds__(256) void prep(const float* __restrict__ in,
                                            const float* __restrict__ pos,
                                            __half* __restrict__ ft,
                                            __half* __restrict__ EYf,
                                            float* __restrict__ SG) {
    __shared__ float tile[128][33];
    __shared__ float red[4][64];
    const int bb  = blockIdx.x;
    const int tid = threadIdx.x;
    if (bb < 1024) {
        const int bx = bb & 31, eb2 = (bb >> 5) & 7, b = bb >> 8;
        const int n0 = bx * 128;
        const int rn = tid >> 3, re = (tid & 7) * 4;
#pragma unroll
        for (int p = 0; p < 4; p++) {
            const int n = p * 32 + rn;
            float4 v = *(const float4*)&in[(size_t)(b * NN + n0 + n) * NE + eb2 * 32 + re];
            tile[n][re] = v.x; tile[n][re + 1] = v.y; tile[n][re + 2] = v.z; tile[n][re + 3] = v.w;
        }
        __syncthreads();
#pragma unroll
        for (int i = 0; i < 2; i++) {
            const int c = i * 256 + tid;
            const int l = c & 63, kb_l = c >> 6;
            const int nbase = kb_l * 16 + ((l >> 5) << 3);
            const int col = l & 31;
            __half hh[8];
#pragma unroll
            for (int j = 0; j < 8; j++) hh[j] = __float2half_rn(tile[nbase + j][col]);
            const size_t idx = ((((size_t)b * 256 + (size_t)bx * 8 + kb_l) * 8 + eb2) * 64 + l) * 8;
            *(uint4*)&ft[idx] = *(const uint4*)hh;
        }
    } else if (bb < 2048) {
        const int base = (bb - 1024) * 1024 + tid * 4;
        const int j0 = base & 7;
        const int l  = (base >> 3) & 63;
        const int rt = (base >> 9) & 1;
        const int kb = (base >> 10) & 255;
        const int b  = base >> 18;
        const int r  = rt * 32 + (l & 31);
        const int k0 = kb * 16 + ((l >> 5) << 3) + j0;
        const float ry = (float)r * (1.0f / 63.0f);
        __half hh[4];
#pragma unroll
        for (int jj = 0; jj < 4; jj++) {
            const float y = pos[((size_t)b * NN + k0 + jj) * 2 + 1];
            const float d = ry - y;
            hh[jj] = __float2half_rn(__expf(d * d * -50.0f));
        }
        *(uint2*)&EYf[base] = *(const uint2*)hh;
    } else {
        const int idx = bb - 2048;
        const int b   = idx >> 8;
        const int gx  = (idx >> 2) & 63;
        const int kh  = idx & 3;
        const int gy  = tid & 63, kq = tid >> 6;
        const float gxv = (float)gx * (1.0f / 63.0f);
        const float gyv = (float)gy * (1.0f / 63.0f);
        const float2* pb = (const float2*)(pos + (size_t)b * NN * 2);
        float s = 0.f;
        const int kbase = kh * 1024 + kq * 256;
#pragma unroll 4
        for (int i = 0; i < 256; ++i) {
            const float2 p2 = pb[kbase + i];
            const float dx = gxv - p2.x, dy = gyv - p2.y;
            const _Float16 exh = (_Float16)__expf(dx * dx * -50.0f);
            const _Float16 eyh = (_Float16)__expf(dy * dy * -50.0f);
            s += (float)(_Float16)(exh * eyh);   // replicate GEMM's f16 product rounding
        }
        red[kq][gy] = s;
        __syncthreads();
        if (tid < 64) {
            const float tot = red[0][tid] + red[1][tid] + red[2][tid] + red[3][tid];
            atomicAdd(&SG[(size_t)b * 4096 + gx * 64 + tid], tot);
        }
    }
}

// ---------- fused GEMM. 512 blocks x 512 thr (2 blocks/CU, 4 waves/SIMD).
// 64 K-64 sub-rounds in 32 spans; barrier + vmcnt once per span.
__global__ __launch_bounds__(512, 4) void nw_gemm(const __half* __restrict__ FT,
                                                  const __half* __restrict__ EYf,
                                                  const float* __restrict__ pos,
                                                  const float* __restrict__ SG,
                                                  float* __restrict__ out) {
    __shared__ __half Bs[6][4096];       // 48 KB, 6-buffer rotation (8 KB tiles)
    __shared__ __half exb[2][4096];      // 16 KB ex rows (gx = 2mblk+g)
    __shared__ float Sinv_s[128];

    const int bid  = blockIdx.x;
    const int xcd  = bid & 7;            // pin (b, e-half) per XCD
    const int b    = xcd >> 1;
    const int etp  = xcd & 1;
    const int rest = bid >> 3;
    const int et   = etp * 2 + (rest & 1);   // e-quarter (64 e)
    const int mblk = rest >> 1;              // 0..31
    const int tid  = threadIdx.x;
    const int wave = tid >> 6, lane = tid & 63;
    const int g   = wave & 1;                // m-half
    const int kw  = wave >> 1;               // k-quarter of 64
    const int kwo = kw * 16 + ((lane >> 5) << 3);

    const __half* ft_t = FT + ((size_t)(b * 256 + (tid >> 7)) * 8 + et * 2) * 512
                            + (size_t)(tid & 127) * 8;
    const __half* eyW = EYf + ((size_t)b << 18) + (size_t)lane * 8;
    const int bdst = (tid >> 7) * 1024 + (tid & 127) * 8;
    const int rdO  = kw * 1024 + lane * 8;
    const __half* exg = exb[g];

#define STAGE(rr, QP_) gload_lds16(ft_t + (size_t)(rr) * 16384, (QP_) + bdst)

    // ---- prologue: stage tiles 0..3, ey(0), Sinv, ex rows, full drain
    STAGE(0, &Bs[0][0]);
    STAGE(1, &Bs[1][0]);
    STAGE(2, &Bs[2][0]);
    STAGE(3, &Bs[3][0]);
    half8 eyN0 = *(const half8*)(eyW + (size_t)((kw * 2    ) * 512));
    half8 eyN1 = *(const half8*)(eyW + (size_t)((kw * 2 + 1) * 512));
    if (tid < 128) {
        const float sg = SG[(size_t)b * 4096 + mblk * 128 + tid];
        Sinv_s[tid] = 1.0f / (sg + 1e-8f);
    }
    {
        const float* pb = pos + (size_t)b * NN * 2;
        const float gx0 = (float)(mblk * 2)     * (1.0f / 63.0f);
        const float gx1 = (float)(mblk * 2 + 1) * (1.0f / 63.0f);
        for (int k = tid; k < NN; k += 512) {
            const float x = pb[2 * k];
            const float d0 = gx0 - x, d1 = gx1 - x;
            exb[0][k] = __float2half_rn(__expf(d0 * d0 * -50.0f));
            exb[1][k] = __float2half_rn(__expf(d1 * d1 * -50.0f));
        }
    }
    __syncthreads();   // tiles 0..3 + ey(0) landed; ex/Sinv ready

    floatx16 acc00 = {}, acc01 = {}, acc10 = {}, acc11 = {};
    half8 aA0, aA1, bfA0, bfA1, aB0, aB1, bfB0, bfB1, exN;

    // frags(0) -> A set; a(0) = ex(0)*ey(0); issue ey(1)
    bfA0 = *(const half8*)(&Bs[0][0] + rdO);
    bfA1 = *(const half8*)(&Bs[0][0] + rdO + 512);
    {
        half8 e0 = *(const half8*)(exg + kwo);
        aA0 = e0 * eyN0; aA1 = e0 * eyN1;
    }
    eyN0 = *(const half8*)(eyW + (size_t)(((1 * 4 + kw) * 2    ) * 512));
    eyN1 = *(const half8*)(eyW + (size_t)(((1 * 4 + kw) * 2 + 1) * 512));

    __half *q0 = &Bs[0][0], *q1 = &Bs[1][0], *q2 = &Bs[2][0],
           *q3 = &Bs[3][0], *q4 = &Bs[4][0], *q5 = &Bs[5][0];

    for (int t = 0; t < 32; ++t) {
        const int rA = 2 * t;
        // ======== sub-round rA (even): compute A=frags(rA); read frags(rA+1)->B
        if (t < 30) STAGE(rA + 4, q4);
        __builtin_amdgcn_sched_barrier(0);
        {
            bfB0 = *(const half8*)(q1 + rdO);
            bfB1 = *(const half8*)(q1 + rdO + 512);
            exN  = *(const half8*)(exg + (rA + 1) * 64 + kwo);
        }
        __builtin_amdgcn_s_setprio(1);
        acc00 = MFMA32(aA0, bfA0, acc00);
        acc01 = MFMA32(aA0, bfA1, acc01);
        acc10 = MFMA32(aA1, bfA0, acc10);
        acc11 = MFMA32(aA1, bfA1, acc11);
        __builtin_amdgcn_s_setprio(0);
        aB0 = exN * eyN0; aB1 = exN * eyN1;          // consumes ey(rA+1)
        __builtin_amdgcn_sched_barrier(0);
        if (t < 31) {                                 // issue ey(rA+2)
            eyN0 = *(const half8*)(eyW + (size_t)((((rA + 2) * 4 + kw) * 2    ) * 512));
            eyN1 = *(const half8*)(eyW + (size_t)((((rA + 2) * 4 + kw) * 2 + 1) * 512));
        }
        __builtin_amdgcn_sched_barrier(0);

        // ======== sub-round rA+1 (odd): compute B=frags(rA+1); read frags(rA+2)->A
        if (t < 30) STAGE(rA + 5, q5);
        __builtin_amdgcn_sched_barrier(0);
        if (t < 31) {
            bfA0 = *(const half8*)(q2 + rdO);
            bfA1 = *(const half8*)(q2 + rdO + 512);
            exN  = *(const half8*)(exg + (rA + 2) * 64 + kwo);
        }
        __builtin_amdgcn_s_setprio(1);
        acc00 = MFMA32(aB0, bfB0, acc00);
        acc01 = MFMA32(aB0, bfB1, acc01);
        acc10 = MFMA32(aB1, bfB0, acc10);
        acc11 = MFMA32(aB1, bfB1, acc11);
        __builtin_amdgcn_s_setprio(0);
        if (t < 31) { aA0 = exN * eyN0; aA1 = exN * eyN1; }   // consumes ey(rA+2)
        __builtin_amdgcn_sched_barrier(0);
        if (t < 31) {                                 // issue ey(rA+3)
            eyN0 = *(const half8*)(eyW + (size_t)((((rA + 3) * 4 + kw) * 2    ) * 512));
            eyN1 = *(const half8*)(eyW + (size_t)((((rA + 3) * 4 + kw) * 2 + 1) * 512));
        }
        __builtin_amdgcn_sched_barrier(0);
        if (t < 31) { asm volatile("s_waitcnt vmcnt(3)" ::: "memory"); }
        else        { asm volatile("s_waitcnt vmcnt(0)" ::: "memory"); }
        __builtin_amdgcn_s_barrier();
        // rotate buffers: q_i <- q_{i+2}
        {
            __half *t0 = q0, *t1 = q1;
            q0 = q2; q1 = q3; q2 = q4; q3 = q5; q4 = t0; q5 = t1;
        }
    }
#undef STAGE

    __syncthreads();

    // ---- k-split reduce through freed Bs pool (48 KB) + normalize + store.
    // D layout: col(e)=lane&31, row = (reg&3) + 8*(reg>>2) + 4*(lane>>5)
    float* RS = (float*)&Bs[0][0];   // 12288 floats

#define RSWRITE(A0_, A1_) do {                                                    \
        if (kw > 0) {                                                             \
            *(floatx16*)&RS[((0 * 2 + g) * 3 + (kw - 1)) * 1024 + lane * 16] = A0_; \
            *(floatx16*)&RS[((1 * 2 + g) * 3 + (kw - 1)) * 1024 + lane * 16] = A1_; \
        }                                                                         \
    } while (0)

#define RSREDUCE(A0_, A1_, RT_) do {                                              \
        if (kw == 0) {                                                            \
            _Pragma("unroll")                                                     \
            for (int qq = 0; qq < 2; qq++) {                                      \
                floatx16 a = qq ? A1_ : A0_;                                      \
                const int rb = ((qq * 2 + g) * 3) * 1024 + lane * 16;             \
                a += *(const floatx16*)&RS[rb];                                   \
                a += *(const floatx16*)&RS[rb + 1024];                            \
                a += *(const floatx16*)&RS[rb + 2048];                            \
                const int e = et * 64 + qq * 32 + (lane & 31);                    \
                float* orow = out + ((size_t)b * NE + e) * NP                     \
                                  + mblk * 128 + g * 64 + (RT_) * 32;             \
                _Pragma("unroll")                                                 \
                for (int q = 0; q < 4; ++q) {                                     \
                    const int pr = q * 8 + ((lane >> 5) << 2);                    \
                    const floatx4 sv = *(const floatx4*)&Sinv_s[g * 64 + (RT_) * 32 + pr]; \
                    floatx4 o;                                                    \
                    o.x = a[q * 4 + 0] * sv.x; o.y = a[q * 4 + 1] * sv.y;         \
                    o.z = a[q * 4 + 2] * sv.z; o.w = a[q * 4 + 3] * sv.w;         \
                    *(floatx4*)&orow[pr] = o;                                     \
                }                                                                 \
            }                                                                     \
        }                                                                         \
    } while (0)

    RSWRITE(acc00, acc01);
    __syncthreads();
    RSREDUCE(acc00, acc01, 0);
    __syncthreads();
    RSWRITE(acc10, acc11);
    __syncthreads();
    RSREDUCE(acc10, acc11, 1);

#undef RSWRITE
#undef RSREDUCE
}

extern "C" void kernel_launch(void* const* d_in, const int* in_sizes, int n_in,
                              void* d_out, int out_size, void* d_ws, size_t ws_size,
                              hipStream_t stream) {
    const float* feat = (const float*)d_in[0];   // [4][4096][256] f32
    const float* pos  = (const float*)d_in[1];   // [4][4096][2]  f32
    float* out = (float*)d_out;                  // [4][256][4096] f32
    __half* FT  = (__half*)d_ws;                                       // 8.39 MB
    __half* EYf = (__half*)((char*)d_ws + 8388608);                    // +2.10 MB
    float*  SG  = (float*)((char*)d_ws + 8388608 + 2097152);           // +64 KB

    hipMemsetAsync(SG, 0, (size_t)NB * 4096 * sizeof(float), stream);
    hipLaunchKernelGGL(prep, dim3(3072), dim3(256), 0, stream, feat, pos, FT, EYf, SG);
    hipLaunchKernelGGL(nw_gemm, dim3(512), dim3(512), 0, stream, FT, EYf, pos, SG, out);
}

// Round 10
// 121.120 us; speedup vs baseline: 2.9158x; 1.3190x over previous
//
#include <hip/hip_runtime.h>
#include <hip/hip_fp16.h>

// NeuronToSpatialGrid R12: R11 (barrier-free GEMM loop, operands direct from L2)
// + the missing __syncthreads() between the K-loop and the epilogue's reuse of
// the LDS pool. R11's NaN was a race: out-of-phase waves' RSWRITE corrupted exb
// (pool bytes 24576..40959) while slow waves still read it in their K-loop.

typedef __attribute__((ext_vector_type(8))) _Float16 half8;
typedef __attribute__((ext_vector_type(2))) _Float16 half2v;
typedef __attribute__((ext_vector_type(4))) float floatx4;
typedef __attribute__((ext_vector_type(16))) float floatx16;

#define NB 4
#define NN 4096
#define NE 256
#define NP 4096

#if defined(__has_builtin)
#if __has_builtin(__builtin_amdgcn_fdot2)
#define HAVE_FDOT2 1
#endif
#endif

__device__ inline float sum8(half8 v, float s) {
#ifdef HAVE_FDOT2
    half2v one; one[0] = (_Float16)1.0f; one[1] = (_Float16)1.0f;
    half2v* p = (half2v*)&v;
#pragma unroll
    for (int j = 0; j < 4; j++) s = __builtin_amdgcn_fdot2(p[j], one, s, false);
#else
#pragma unroll
    for (int j = 0; j < 8; j++) s += (float)v[j];
#endif
    return s;
}

#define MFMA32(a, bb, c) __builtin_amdgcn_mfma_f32_32x32x16_f16(a, bb, c, 0, 0, 0)

// ---------- prep (verbatim R7, verified): [0,1024) F transpose -> FT frag order;
// [1024,2048) EY frag order.
// FT: idx = (((b*256+kb)*8+eb)*64+l)*8+j = F[b][kb*16+(l>>5)*8+j][eb*32+(l&31)]
// EY: idx = (((b*256+kb)*2+rt)*64+l)*8+j = exp(-50*(r/63-y_k)^2),
//   r = rt*32+(l&31), k = kb*16+(l>>5)*8+j
__global__ __launch_bounds__(256) void prep(const float* __restrict__ in,
                                            const float* __restrict__ pos,
                                            __half* __restrict__ ft,
                                            __half* __restrict__ EYf) {
    const int bb  = blockIdx.x;
    const int tid = threadIdx.x;
    if (bb < 1024) {
        __shared__ float tile[128][33];
        const int bx = bb & 31, eb2 = (bb >> 5) & 7, b = bb >> 8;
        const int n0 = bx * 128;
        const int rn = tid >> 3, re = (tid & 7) * 4;
#pragma unroll
        for (int p = 0; p < 4; p++) {
            const int n = p * 32 + rn;
            float4 v = *(const float4*)&in[(size_t)(b * NN + n0 + n) * NE + eb2 * 32 + re];
            tile[n][re] = v.x; tile[n][re + 1] = v.y; tile[n][re + 2] = v.z; tile[n][re + 3] = v.w;
        }
        __syncthreads();
#pragma unroll
        for (int i = 0; i < 2; i++) {
            const int c = i * 256 + tid;
            const int l = c & 63, kb_l = c >> 6;
            const int nbase = kb_l * 16 + ((l >> 5) << 3);
            const int col = l & 31;
            __half hh[8];
#pragma unroll
            for (int j = 0; j < 8; j++) hh[j] = __float2half_rn(tile[nbase + j][col]);
            const size_t idx = ((((size_t)b * 256 + (size_t)bx * 8 + kb_l) * 8 + eb2) * 64 + l) * 8;
            *(uint4*)&ft[idx] = *(const uint4*)hh;
        }
    } else {
        const int base = (bb - 1024) * 1024 + tid * 4;
        const int j0 = base & 7;
        const int l  = (base >> 3) & 63;
        const int rt = (base >> 9) & 1;
        const int kb = (base >> 10) & 255;
        const int b  = base >> 18;
        const int r  = rt * 32 + (l & 31);
        const int k0 = kb * 16 + ((l >> 5) << 3) + j0;
        const float ry = (float)r * (1.0f / 63.0f);
        __half hh[4];
#pragma unroll
        for (int jj = 0; jj < 4; jj++) {
            const float y = pos[((size_t)b * NN + k0 + jj) * 2 + 1];
            const float d = ry - y;
            hh[jj] = __float2half_rn(__expf(d * d * -50.0f));
        }
        *(uint2*)&EYf[base] = *(const uint2*)hh;
    }
}

// ---------- fused GEMM. 512 blocks x 512 thr (2 blocks/CU, 16 waves/CU).
// Wave (g,kw): 64m x 64e tile, k-slice kw of each K-64 round. All operands
// (bf0,bf1,ey0,ey1) from global/L2; ex from LDS. NO barrier in the loop.
__global__ __launch_bounds__(512, 4) void nw_gemm(const __half* __restrict__ FT,
                                                  const __half* __restrict__ EYf,
                                                  const float* __restrict__ pos,
                                                  float* __restrict__ out) {
    __shared__ __align__(64) char pool[49152];   // run: exb at +24KB; epi: RS 48KB
    __shared__ float S_s[4][128];
    __shared__ float Sinv_s[128];

    __half* exb = (__half*)pool + 12288;          // 2 x 4096 halfs (16 KB)

    const int bid  = blockIdx.x;
    const int xcd  = bid & 7;            // pin (b, e-half): FT-half 1MB + EY 512KB in L2
    const int b    = xcd >> 1;
    const int etp  = xcd & 1;
    const int rest = bid >> 3;
    const int et   = etp * 2 + (rest & 1);   // e-quarter (64 e)
    const int mblk = rest >> 1;              // 0..31
    const int tid  = threadIdx.x;
    const int wave = tid >> 6, lane = tid & 63;
    const int g   = wave & 1;                // m-half (gx = 2*mblk + g)
    const int kw  = wave >> 1;               // k-quarter of each K-64 round
    const int kwo = kw * 16 + ((lane >> 5) << 3);

    // per-wave streams (frag order): kb = 4r + kw
    const __half* ftq = FT + ((size_t)(b * 256 + kw) * 8 + et * 2) * 512 + (size_t)lane * 8;
    const __half* eyq = EYf + ((size_t)b << 18) + (size_t)(kw * 2) * 512 + (size_t)lane * 8;
    const __half* exq = exb + g * 4096 + kwo;

    // ---- prologue: build ex rows (the only in-loop LDS data)
    {
        const float* pb = pos + (size_t)b * NN * 2;
        const float gx0 = (float)(mblk * 2)     * (1.0f / 63.0f);
        const float gx1 = (float)(mblk * 2 + 1) * (1.0f / 63.0f);
        for (int k = tid; k < NN; k += 512) {
            const float x = pb[2 * k];
            const float d0 = gx0 - x, d1 = gx1 - x;
            exb[k]        = __float2half_rn(__expf(d0 * d0 * -50.0f));
            exb[4096 + k] = __float2half_rn(__expf(d1 * d1 * -50.0f));
        }
    }
    __syncthreads();   // exb ready

    floatx16 acc00 = {}, acc01 = {}, acc10 = {}, acc11 = {};
    float s0 = 0.f, s1 = 0.f;

    // ---- barrier-free K-loop: 64 steps of K-16 per wave
    for (int r = 0; r < 64; ++r) {
        const half8 bf0 = *(const half8*)(ftq);
        const half8 bf1 = *(const half8*)(ftq + 512);
        const half8 ey0 = *(const half8*)(eyq);
        const half8 ey1 = *(const half8*)(eyq + 512);
        const half8 ex8 = *(const half8*)(exq);
        ftq += 16384; eyq += 4096; exq += 64;
        half8 a = ex8 * ey0;
        s0 = sum8(a, s0);
        acc00 = MFMA32(a, bf0, acc00);
        acc01 = MFMA32(a, bf1, acc01);
        a = ex8 * ey1;
        s1 = sum8(a, s1);
        acc10 = MFMA32(a, bf0, acc10);
        acc11 = MFMA32(a, bf1, acc11);
    }

    __syncthreads();   // R12 FIX: all waves done reading exb before pool reuse

    // ---- row-sum partials (wave (g,kw) covered k = r*64 + kw*16 + hi8 + j)
    s0 += __shfl_xor(s0, 32, 64);
    s1 += __shfl_xor(s1, 32, 64);
    if (lane < 32) {
        S_s[kw][g * 64 + lane]      = s0;
        S_s[kw][g * 64 + 32 + lane] = s1;
    }

    // ---- k-split reduce through the pool (48 KB) + normalize + store
    float* RS = (float*)pool;   // 12288 floats

#define RSWRITE(A0_, A1_) do {                                                    \
        if (kw > 0) {                                                             \
            *(floatx16*)&RS[((0 * 2 + g) * 3 + (kw - 1)) * 1024 + lane * 16] = A0_; \
            *(floatx16*)&RS[((1 * 2 + g) * 3 + (kw - 1)) * 1024 + lane * 16] = A1_; \
        }                                                                         \
    } while (0)

#define RSREDUCE(A0_, A1_, RT_) do {                                              \
        if (kw == 0) {                                                            \
            _Pragma("unroll")                                                     \
            for (int qq = 0; qq < 2; qq++) {                                      \
                floatx16 a = qq ? A1_ : A0_;                                      \
                const int rb = ((qq * 2 + g) * 3) * 1024 + lane * 16;             \
                a += *(const floatx16*)&RS[rb];                                   \
                a += *(const floatx16*)&RS[rb + 1024];                            \
                a += *(const floatx16*)&RS[rb + 2048];                            \
                const int e = et * 64 + qq * 32 + (lane & 31);                    \
                float* orow = out + ((size_t)b * NE + e) * NP                     \
                                  + mblk * 128 + g * 64 + (RT_) * 32;             \
                _Pragma("unroll")                                                 \
                for (int q = 0; q < 4; ++q) {                                     \
                    const int pr = q * 8 + ((lane >> 5) << 2);                    \
                    const floatx4 sv = *(const floatx4*)&Sinv_s[g * 64 + (RT_) * 32 + pr]; \
                    floatx4 o;                                                    \
                    o.x = a[q * 4 + 0] * sv.x; o.y = a[q * 4 + 1] * sv.y;         \
                    o.z = a[q * 4 + 2] * sv.z; o.w = a[q * 4 + 3] * sv.w;         \
                    *(floatx4*)&orow[pr] = o;                                     \
                }                                                                 \
            }                                                                     \
        }                                                                         \
    } while (0)

    RSWRITE(acc00, acc01);
    __syncthreads();
    if (tid < 128)
        Sinv_s[tid] = 1.0f / (S_s[0][tid] + S_s[1][tid] + S_s[2][tid] + S_s[3][tid] + 1e-8f);
    __syncthreads();
    RSREDUCE(acc00, acc01, 0);
    __syncthreads();
    RSWRITE(acc10, acc11);
    __syncthreads();
    RSREDUCE(acc10, acc11, 1);

#undef RSWRITE
#undef RSREDUCE
}

extern "C" void kernel_launch(void* const* d_in, const int* in_sizes, int n_in,
                              void* d_out, int out_size, void* d_ws, size_t ws_size,
                              hipStream_t stream) {
    const float* feat = (const float*)d_in[0];   // [4][4096][256] f32
    const float* pos  = (const float*)d_in[1];   // [4][4096][2]  f32
    float* out = (float*)d_out;                  // [4][256][4096] f32
    __half* FT  = (__half*)d_ws;                                       // 8.39 MB (frag order)
    __half* EYf = (__half*)((char*)d_ws + 8388608);                    // +2.10 MB (frag order)

    hipLaunchKernelGGL(prep, dim3(2048), dim3(256), 0, stream, feat, pos, FT, EYf);
    hipLaunchKernelGGL(nw_gemm, dim3(512), dim3(512), 0, stream, FT, EYf, pos, out);
}

// Round 11
// 116.414 us; speedup vs baseline: 3.0337x; 1.0404x over previous
//
#include <hip/hip_runtime.h>
#include <hip/hip_fp16.h>

// NeuronToSpatialGrid R13: R12 (barrier-free, operands direct from L2) + register
// double-buffer on the operand stream: iteration r issues r+1's 5 loads into the
// N-set before computing from the C-set (unroll x2 swaps sets, no copies).
// R12 postmortem: flat 57us at 23% everything = load-use latency, not convoy/BW.

typedef __attribute__((ext_vector_type(8))) _Float16 half8;
typedef __attribute__((ext_vector_type(2))) _Float16 half2v;
typedef __attribute__((ext_vector_type(4))) float floatx4;
typedef __attribute__((ext_vector_type(16))) float floatx16;

#define NB 4
#define NN 4096
#define NE 256
#define NP 4096

#if defined(__has_builtin)
#if __has_builtin(__builtin_amdgcn_fdot2)
#define HAVE_FDOT2 1
#endif
#endif

__device__ inline float sum8(half8 v, float s) {
#ifdef HAVE_FDOT2
    half2v one; one[0] = (_Float16)1.0f; one[1] = (_Float16)1.0f;
    half2v* p = (half2v*)&v;
#pragma unroll
    for (int j = 0; j < 4; j++) s = __builtin_amdgcn_fdot2(p[j], one, s, false);
#else
#pragma unroll
    for (int j = 0; j < 8; j++) s += (float)v[j];
#endif
    return s;
}

#define MFMA32(a, bb, c) __builtin_amdgcn_mfma_f32_32x32x16_f16(a, bb, c, 0, 0, 0)

// ---------- prep (verbatim R7/R12, verified): [0,1024) F transpose -> FT frag
// order; [1024,2048) EY frag order.
// FT: idx = (((b*256+kb)*8+eb)*64+l)*8+j = F[b][kb*16+(l>>5)*8+j][eb*32+(l&31)]
// EY: idx = (((b*256+kb)*2+rt)*64+l)*8+j = exp(-50*(r/63-y_k)^2),
//   r = rt*32+(l&31), k = kb*16+(l>>5)*8+j
__global__ __launch_bounds__(256) void prep(const float* __restrict__ in,
                                            const float* __restrict__ pos,
                                            __half* __restrict__ ft,
                                            __half* __restrict__ EYf) {
    const int bb  = blockIdx.x;
    const int tid = threadIdx.x;
    if (bb < 1024) {
        __shared__ float tile[128][33];
        const int bx = bb & 31, eb2 = (bb >> 5) & 7, b = bb >> 8;
        const int n0 = bx * 128;
        const int rn = tid >> 3, re = (tid & 7) * 4;
#pragma unroll
        for (int p = 0; p < 4; p++) {
            const int n = p * 32 + rn;
            float4 v = *(const float4*)&in[(size_t)(b * NN + n0 + n) * NE + eb2 * 32 + re];
            tile[n][re] = v.x; tile[n][re + 1] = v.y; tile[n][re + 2] = v.z; tile[n][re + 3] = v.w;
        }
        __syncthreads();
#pragma unroll
        for (int i = 0; i < 2; i++) {
            const int c = i * 256 + tid;
            const int l = c & 63, kb_l = c >> 6;
            const int nbase = kb_l * 16 + ((l >> 5) << 3);
            const int col = l & 31;
            __half hh[8];
#pragma unroll
            for (int j = 0; j < 8; j++) hh[j] = __float2half_rn(tile[nbase + j][col]);
            const size_t idx = ((((size_t)b * 256 + (size_t)bx * 8 + kb_l) * 8 + eb2) * 64 + l) * 8;
            *(uint4*)&ft[idx] = *(const uint4*)hh;
        }
    } else {
        const int base = (bb - 1024) * 1024 + tid * 4;
        const int j0 = base & 7;
        const int l  = (base >> 3) & 63;
        const int rt = (base >> 9) & 1;
        const int kb = (base >> 10) & 255;
        const int b  = base >> 18;
        const int r  = rt * 32 + (l & 31);
        const int k0 = kb * 16 + ((l >> 5) << 3) + j0;
        const float ry = (float)r * (1.0f / 63.0f);
        __half hh[4];
#pragma unroll
        for (int jj = 0; jj < 4; jj++) {
            const float y = pos[((size_t)b * NN + k0 + jj) * 2 + 1];
            const float d = ry - y;
            hh[jj] = __float2half_rn(__expf(d * d * -50.0f));
        }
        *(uint2*)&EYf[base] = *(const uint2*)hh;
    }
}

// ---------- fused GEMM. 512 blocks x 512 thr (2 blocks/CU, 16 waves/CU).
// Wave (g,kw): 64m x 64e tile, k-slice kw of each K-64 round. Operands from
// global/L2 + ex from LDS, register double-buffered. NO barrier in the loop.
__global__ __launch_bounds__(512, 4) void nw_gemm(const __half* __restrict__ FT,
                                                  const __half* __restrict__ EYf,
                                                  const float* __restrict__ pos,
                                                  float* __restrict__ out) {
    __shared__ __align__(64) char pool[49152];   // run: exb at +24KB; epi: RS 48KB
    __shared__ float S_s[4][128];
    __shared__ float Sinv_s[128];

    __half* exb = (__half*)pool + 12288;          // 2 x 4096 halfs (16 KB)

    const int bid  = blockIdx.x;
    const int xcd  = bid & 7;            // pin (b, e-half): FT-half 1MB + EY 512KB in L2
    const int b    = xcd >> 1;
    const int etp  = xcd & 1;
    const int rest = bid >> 3;
    const int et   = etp * 2 + (rest & 1);   // e-quarter (64 e)
    const int mblk = rest >> 1;              // 0..31
    const int tid  = threadIdx.x;
    const int wave = tid >> 6, lane = tid & 63;
    const int g   = wave & 1;                // m-half (gx = 2*mblk + g)
    const int kw  = wave >> 1;               // k-quarter of each K-64 round
    const int kwo = kw * 16 + ((lane >> 5) << 3);

    // per-wave streams (frag order): kb = 4r + kw
    const __half* ftb = FT + ((size_t)(b * 256 + kw) * 8 + et * 2) * 512 + (size_t)lane * 8;
    const __half* eyb = EYf + ((size_t)b << 18) + (size_t)(kw * 2) * 512 + (size_t)lane * 8;
    const __half* exq = exb + g * 4096 + kwo;

    // ---- prologue: build ex rows (the only in-loop LDS data)
    {
        const float* pb = pos + (size_t)b * NN * 2;
        const float gx0 = (float)(mblk * 2)     * (1.0f / 63.0f);
        const float gx1 = (float)(mblk * 2 + 1) * (1.0f / 63.0f);
        for (int k = tid; k < NN; k += 512) {
            const float x = pb[2 * k];
            const float d0 = gx0 - x, d1 = gx1 - x;
            exb[k]        = __float2half_rn(__expf(d0 * d0 * -50.0f));
            exb[4096 + k] = __float2half_rn(__expf(d1 * d1 * -50.0f));
        }
    }
    __syncthreads();   // exb ready

    floatx16 acc00 = {}, acc01 = {}, acc10 = {}, acc11 = {};
    float s0 = 0.f, s1 = 0.f;

    // C-set (current) / N-set (next) register double-buffer
    half8 bfC0, bfC1, eyC0, eyC1, exC, bfN0, bfN1, eyN0, eyN1, exN;

    // load set for r=0
    bfC0 = *(const half8*)(ftb);
    bfC1 = *(const half8*)(ftb + 512);
    eyC0 = *(const half8*)(eyb);
    eyC1 = *(const half8*)(eyb + 512);
    exC  = *(const half8*)(exq);

#define ITER(r_, cb0,cb1,ce0,ce1,cx, nb0,nb1,ne0,ne1,nx) do {          \
    const int rn_ = ((r_) + 1) & 63;                                   \
    nb0 = *(const half8*)(ftb + (size_t)rn_ * 16384);                  \
    nb1 = *(const half8*)(ftb + (size_t)rn_ * 16384 + 512);            \
    ne0 = *(const half8*)(eyb + (size_t)rn_ * 4096);                   \
    ne1 = *(const half8*)(eyb + (size_t)rn_ * 4096 + 512);             \
    nx  = *(const half8*)(exq + rn_ * 64);                             \
    __builtin_amdgcn_sched_barrier(0);                                 \
    half8 a0_ = cx * ce0;                                              \
    s0 = sum8(a0_, s0);                                                \
    half8 a1_ = cx * ce1;                                              \
    s1 = sum8(a1_, s1);                                                \
    __builtin_amdgcn_s_setprio(1);                                     \
    acc00 = MFMA32(a0_, cb0, acc00);                                   \
    acc01 = MFMA32(a0_, cb1, acc01);                                   \
    acc10 = MFMA32(a1_, cb0, acc10);                                   \
    acc11 = MFMA32(a1_, cb1, acc11);                                   \
    __builtin_amdgcn_s_setprio(0);                                     \
} while (0)

    for (int t = 0; t < 32; ++t) {
        ITER(2 * t,     bfC0,bfC1,eyC0,eyC1,exC, bfN0,bfN1,eyN0,eyN1,exN);
        ITER(2 * t + 1, bfN0,bfN1,eyN0,eyN1,exN, bfC0,bfC1,eyC0,eyC1,exC);
    }
#undef ITER

    __syncthreads();   // all waves done reading exb before pool reuse

    // ---- row-sum partials (wave (g,kw) covered k = r*64 + kw*16 + hi8 + j)
    s0 += __shfl_xor(s0, 32, 64);
    s1 += __shfl_xor(s1, 32, 64);
    if (lane < 32) {
        S_s[kw][g * 64 + lane]      = s0;
        S_s[kw][g * 64 + 32 + lane] = s1;
    }

    // ---- k-split reduce through the pool (48 KB) + normalize + store
    float* RS = (float*)pool;   // 12288 floats

#define RSWRITE(A0_, A1_) do {                                                    \
        if (kw > 0) {                                                             \
            *(floatx16*)&RS[((0 * 2 + g) * 3 + (kw - 1)) * 1024 + lane * 16] = A0_; \
            *(floatx16*)&RS[((1 * 2 + g) * 3 + (kw - 1)) * 1024 + lane * 16] = A1_; \
        }                                                                         \
    } while (0)

#define RSREDUCE(A0_, A1_, RT_) do {                                              \
        if (kw == 0) {                                                            \
            _Pragma("unroll")                                                     \
            for (int qq = 0; qq < 2; qq++) {                                      \
                floatx16 a = qq ? A1_ : A0_;                                      \
                const int rb = ((qq * 2 + g) * 3) * 1024 + lane * 16;             \
                a += *(const floatx16*)&RS[rb];                                   \
                a += *(const floatx16*)&RS[rb + 1024];                            \
                a += *(const floatx16*)&RS[rb + 2048];                            \
                const int e = et * 64 + qq * 32 + (lane & 31);                    \
                float* orow = out + ((size_t)b * NE + e) * NP                     \
                                  + mblk * 128 + g * 64 + (RT_) * 32;             \
                _Pragma("unroll")                                                 \
                for (int q = 0; q < 4; ++q) {                                     \
                    const int pr = q * 8 + ((lane >> 5) << 2);                    \
                    const floatx4 sv = *(const floatx4*)&Sinv_s[g * 64 + (RT_) * 32 + pr]; \
                    floatx4 o;                                                    \
                    o.x = a[q * 4 + 0] * sv.x; o.y = a[q * 4 + 1] * sv.y;         \
                    o.z = a[q * 4 + 2] * sv.z; o.w = a[q * 4 + 3] * sv.w;         \
                    *(floatx4*)&orow[pr] = o;                                     \
                }                                                                 \
            }                                                                     \
        }                                                                         \
    } while (0)

    RSWRITE(acc00, acc01);
    __syncthreads();
    if (tid < 128)
        Sinv_s[tid] = 1.0f / (S_s[0][tid] + S_s[1][tid] + S_s[2][tid] + S_s[3][tid] + 1e-8f);
    __syncthreads();
    RSREDUCE(acc00, acc01, 0);
    __syncthreads();
    RSWRITE(acc10, acc11);
    __syncthreads();
    RSREDUCE(acc10, acc11, 1);

#undef RSWRITE
#undef RSREDUCE
}

extern "C" void kernel_launch(void* const* d_in, const int* in_sizes, int n_in,
                              void* d_out, int out_size, void* d_ws, size_t ws_size,
                              hipStream_t stream) {
    const float* feat = (const float*)d_in[0];   // [4][4096][256] f32
    const float* pos  = (const float*)d_in[1];   // [4][4096][2]  f32
    float* out = (float*)d_out;                  // [4][256][4096] f32
    __half* FT  = (__half*)d_ws;                                       // 8.39 MB (frag order)
    __half* EYf = (__half*)((char*)d_ws + 8388608);                    // +2.10 MB (frag order)

    hipLaunchKernelGGL(prep, dim3(2048), dim3(256), 0, stream, feat, pos, FT, EYf);
    hipLaunchKernelGGL(nw_gemm, dim3(512), dim3(512), 0, stream, FT, EYf, pos, out);
}